// Round 1
// baseline (3559.207 us; speedup 1.0000x reference)
//
#include <hip/hip_runtime.h>
#include <hip/hip_bf16.h>
#include <math.h>

#define N_NODES 10000
#define N_EDGES 100000
#define F_IN    128
#define CH      120
#define NH      16
#define NEG_SLOPE 0.2f

// ======================== GEMM (fp32, tiled) ========================
// C[M,Nn] = A[M,K] @ B[K,Nn] (+bias[Nn]) (+ReLU)
#define BM 128
#define BN 128
#define BK 16

template<int ACT>  // 0 = none, 1 = relu
__global__ __launch_bounds__(256) void gemm_kernel(
    const float* __restrict__ A, const float* __restrict__ B,
    const float* __restrict__ bias, float* __restrict__ C,
    int M, int Nn, int K)
{
    __shared__ float As[BM][BK + 1];   // padded: conflict-free column reads
    __shared__ float Bs[BK][BN + 4];
    const int t = threadIdx.x;
    const int tx = t & 15, ty = t >> 4;
    const int row0 = blockIdx.y * BM, col0 = blockIdx.x * BN;

    float acc[8][8];
#pragma unroll
    for (int i = 0; i < 8; ++i)
#pragma unroll
        for (int j = 0; j < 8; ++j) acc[i][j] = 0.f;

    for (int k0 = 0; k0 < K; k0 += BK) {
        // ---- load A tile (128 x 16), float4 per thread x2
#pragma unroll
        for (int l = t; l < BM * BK / 4; l += 256) {
            int m  = l >> 2;
            int kg = (l & 3) << 2;
            int gr = row0 + m, gc = k0 + kg;
            float4 v = make_float4(0.f, 0.f, 0.f, 0.f);
            if (gr < M) {
                if (gc + 3 < K) {
                    v = *reinterpret_cast<const float4*>(A + (size_t)gr * K + gc);
                } else {
                    float tmp[4] = {0.f, 0.f, 0.f, 0.f};
#pragma unroll
                    for (int j = 0; j < 4; ++j)
                        if (gc + j < K) tmp[j] = A[(size_t)gr * K + gc + j];
                    v = make_float4(tmp[0], tmp[1], tmp[2], tmp[3]);
                }
            }
            As[m][kg+0] = v.x; As[m][kg+1] = v.y; As[m][kg+2] = v.z; As[m][kg+3] = v.w;
        }
        // ---- load B tile (16 x 128)
#pragma unroll
        for (int l = t; l < BK * BN / 4; l += 256) {
            int kk = l >> 5;
            int ng = (l & 31) << 2;
            int gk = k0 + kk, gc = col0 + ng;
            float4 v = make_float4(0.f, 0.f, 0.f, 0.f);
            if (gk < K) {
                if (gc + 3 < Nn) {
                    v = *reinterpret_cast<const float4*>(B + (size_t)gk * Nn + gc);
                } else {
                    float tmp[4] = {0.f, 0.f, 0.f, 0.f};
#pragma unroll
                    for (int j = 0; j < 4; ++j)
                        if (gc + j < Nn) tmp[j] = B[(size_t)gk * Nn + gc + j];
                    v = make_float4(tmp[0], tmp[1], tmp[2], tmp[3]);
                }
            }
            Bs[kk][ng+0] = v.x; Bs[kk][ng+1] = v.y; Bs[kk][ng+2] = v.z; Bs[kk][ng+3] = v.w;
        }
        __syncthreads();

#pragma unroll
        for (int kk = 0; kk < BK; ++kk) {
            float a[8], b[8];
#pragma unroll
            for (int j = 0; j < 4; ++j) {
                a[j]     = As[ty * 4 + j][kk];
                a[4 + j] = As[ty * 4 + 64 + j][kk];
                b[j]     = Bs[kk][tx * 4 + j];
                b[4 + j] = Bs[kk][tx * 4 + 64 + j];
            }
#pragma unroll
            for (int i = 0; i < 8; ++i)
#pragma unroll
                for (int j = 0; j < 8; ++j)
                    acc[i][j] = fmaf(a[i], b[j], acc[i][j]);
        }
        __syncthreads();
    }

#pragma unroll
    for (int i = 0; i < 8; ++i) {
        int gr = row0 + ty * 4 + ((i < 4) ? i : (60 + i));
        if (gr >= M) continue;
#pragma unroll
        for (int j = 0; j < 8; ++j) {
            int gc = col0 + tx * 4 + ((j < 4) ? j : (60 + j));
            if (gc >= Nn) continue;
            float v = acc[i][j];
            if (bias) v += bias[gc];
            if (ACT == 1) v = fmaxf(v, 0.f);
            C[(size_t)gr * Nn + gc] = v;
        }
    }
}

// ======================== edge-index dtype handling ========================
// edge_index may be int64 (reference declares it) or int32 (JAX x64 off).
// int64 detection: within the first 2E 32-bit words (safe either way), all
// odd words are zero iff data is int64 (node ids < 2^31, non-negative).
__global__ void detect_kernel(const int* __restrict__ w, int nwords, int* flag)
{
    int i = blockIdx.x * blockDim.x + threadIdx.x;
    int odd = 2 * i + 1;
    if (odd < nwords && w[odd] != 0) atomicOr(flag, 1);
}

__global__ void convert_kernel(const int* __restrict__ w, const int* __restrict__ flag,
                               int* __restrict__ src, int* __restrict__ dst, int E)
{
    int i = blockIdx.x * blockDim.x + threadIdx.x;
    if (i >= E) return;
    if (*flag == 0) {           // int64: [2E int64] = [4E words]
        src[i] = w[2 * i];
        dst[i] = w[2 * E + 2 * i];
    } else {                    // int32
        src[i] = w[i];
        dst[i] = w[E + i];
    }
}

// ======================== attention pieces ========================
// al_src[n,h] = sum_c h[n,h,c]*a_s[h,c] ; al_dst likewise. One wave per (n,h).
__global__ void al_kernel(const float* __restrict__ h,
                          const float* __restrict__ a_s, const float* __restrict__ a_d,
                          float* __restrict__ als, float* __restrict__ ald,
                          int Nn, int Hh, int Cc)
{
    int wid  = (blockIdx.x * blockDim.x + threadIdx.x) >> 6;
    int lane = threadIdx.x & 63;
    if (wid >= Nn * Hh) return;
    int n = wid / Hh, hh = wid - n * Hh;
    const float* hp = h + (size_t)n * Hh * Cc + hh * Cc;
    float s1 = 0.f, s2 = 0.f;
    for (int c = lane; c < Cc; c += 64) {
        float v = hp[c];
        s1 += v * a_s[hh * Cc + c];
        s2 += v * a_d[hh * Cc + c];
    }
#pragma unroll
    for (int off = 32; off; off >>= 1) {
        s1 += __shfl_down(s1, off);
        s2 += __shfl_down(s2, off);
    }
    if (lane == 0) { als[wid] = s1; ald[wid] = s2; }
}

// monotonic float<->uint encoding for atomicMax
__device__ inline unsigned f2enc(float f) {
    unsigned u = __float_as_uint(f);
    return (u & 0x80000000u) ? ~u : (u | 0x80000000u);
}
__device__ inline float enc2f(unsigned k) {
    unsigned u = (k & 0x80000000u) ? (k ^ 0x80000000u) : ~k;
    return __uint_as_float(u);
}

__global__ void edge_max_kernel(const float* __restrict__ als, const float* __restrict__ ald,
                                const int* __restrict__ src, const int* __restrict__ dst,
                                float* __restrict__ ebuf, unsigned* __restrict__ menc,
                                int E, int Hh)
{
    int idx = blockIdx.x * blockDim.x + threadIdx.x;
    if (idx >= E * Hh) return;
    int e = idx / Hh, hh = idx - e * Hh;
    int s = src[e], d = dst[e];
    float v = als[s * Hh + hh] + ald[d * Hh + hh];
    v = (v > 0.f) ? v : NEG_SLOPE * v;   // leaky_relu
    ebuf[idx] = v;
    atomicMax(menc + d * Hh + hh, f2enc(v));
}

__global__ void edge_expsum_kernel(float* __restrict__ ebuf,
                                   const unsigned* __restrict__ menc,
                                   float* __restrict__ den,
                                   const int* __restrict__ dst, int E, int Hh)
{
    int idx = blockIdx.x * blockDim.x + threadIdx.x;
    if (idx >= E * Hh) return;
    int e = idx / Hh, hh = idx - e * Hh;
    int d = dst[e];
    float m  = enc2f(menc[d * Hh + hh]);
    float ex = expf(ebuf[idx] - m);
    ebuf[idx] = ex;
    atomicAdd(den + d * Hh + hh, ex);
}

// out[dst] += h[src] * alpha  (one block per edge)
__global__ void aggregate_kernel(const float* __restrict__ h,
                                 const float* __restrict__ ebuf, const float* __restrict__ den,
                                 const int* __restrict__ src, const int* __restrict__ dst,
                                 float* __restrict__ outp, int Hh, int Cc)
{
    __shared__ float alpha[NH];
    int e = blockIdx.x;
    int s = src[e], d = dst[e];
    int F = Hh * Cc;
    if ((int)threadIdx.x < Hh)
        alpha[threadIdx.x] = ebuf[(size_t)e * Hh + threadIdx.x] / den[d * Hh + threadIdx.x];
    __syncthreads();
    const float* hp = h + (size_t)s * F;
    float* op = outp + (size_t)d * F;
    for (int i = threadIdx.x; i < F; i += blockDim.x)
        atomicAdd(op + i, hp[i] * alpha[i / CH]);
}

// h[i] = act(h[i] + b[i % F]);  act: 0 none, 1 ELU
__global__ void bias_act_kernel(float* __restrict__ h, const float* __restrict__ b,
                                int total, int F, int act)
{
    int i = blockIdx.x * blockDim.x + threadIdx.x;
    if (i >= total) return;
    float v = h[i] + b[i % F];
    if (act == 1) v = (v > 0.f) ? v : expm1f(v);
    h[i] = v;
}

// ======================== launch ========================
extern "C" void kernel_launch(void* const* d_in, const int* in_sizes, int n_in,
                              void* d_out, int out_size, void* d_ws, size_t ws_size,
                              hipStream_t stream)
{
    const float* x   = (const float*)d_in[0];
    const int*   ei  = (const int*)  d_in[1];
    const float* W1  = (const float*)d_in[2];
    const float* a1s = (const float*)d_in[3];
    const float* a1d = (const float*)d_in[4];
    const float* b1  = (const float*)d_in[5];
    const float* W2  = (const float*)d_in[6];
    const float* a2s = (const float*)d_in[7];
    const float* a2d = (const float*)d_in[8];
    const float* b2  = (const float*)d_in[9];
    const float* W3  = (const float*)d_in[10];
    const float* a3s = (const float*)d_in[11];
    const float* a3d = (const float*)d_in[12];
    const float* b3  = (const float*)d_in[13];
    const float* fcW = (const float*)d_in[14];
    const float* fcb = (const float*)d_in[15];

    float* out = (float*)d_out;
    const int N = N_NODES, E = N_EDGES;
    const size_t NF = (size_t)N * NH * CH;   // 19.2M floats

    // Scratch lives inside d_out (400MB; final FC overwrites all of it last).
    // Only the FC input h3 must live outside d_out (FC reads it while writing
    // d_out) -> it goes in d_ws (needs 4.8MB).
    float*    bufA = out;                          // h (post-GEMM)       19.2M
    float*    bufB = bufA + NF;                    // aggregated h        19.2M
    float*    h3a  = bufB + NF;                    // layer3 GEMM out      1.2M
    float*    als  = h3a + (size_t)N * CH;         // [N,16]
    float*    ald  = als + (size_t)N * NH;
    unsigned* menc = (unsigned*)(ald + (size_t)N * NH);
    float*    den  = (float*)(menc + (size_t)N * NH);
    float*    ebuf = den + (size_t)N * NH;         // [E,16]              1.6M
    int*      srcv = (int*)(ebuf + (size_t)E * NH);
    int*      dstv = srcv + E;
    int*      flag = dstv + E;
    float*    h3b  = (float*)d_ws;                 // FC input [N,120]

    // ---- edge index decode (int64-or-int32 robust)
    hipMemsetAsync(flag, 0, sizeof(int), stream);
    detect_kernel <<<(E + 255) / 256, 256, 0, stream>>>(ei, 2 * E, flag);
    convert_kernel<<<(E + 255) / 256, 256, 0, stream>>>(ei, flag, srcv, dstv, E);

    const int F16 = NH * CH;  // 1920
    dim3 gBig((F16 + BN - 1) / BN, (N + BM - 1) / BM);       // (15,79)
    int nEdgeThreads16 = E * NH;

    // =============== layer 1 (H=16) ===============
    gemm_kernel<0><<<gBig, 256, 0, stream>>>(x, W1, nullptr, bufA, N, F16, F_IN);
    al_kernel<<<(N * NH + 3) / 4, 256, 0, stream>>>(bufA, a1s, a1d, als, ald, N, NH, CH);
    hipMemsetAsync(menc, 0, (size_t)N * NH * 4, stream);
    hipMemsetAsync(den,  0, (size_t)N * NH * 4, stream);
    edge_max_kernel   <<<(nEdgeThreads16 + 255) / 256, 256, 0, stream>>>(als, ald, srcv, dstv, ebuf, menc, E, NH);
    edge_expsum_kernel<<<(nEdgeThreads16 + 255) / 256, 256, 0, stream>>>(ebuf, menc, den, dstv, E, NH);
    hipMemsetAsync(bufB, 0, NF * 4, stream);
    aggregate_kernel<<<E, 256, 0, stream>>>(bufA, ebuf, den, srcv, dstv, bufB, NH, CH);
    bias_act_kernel<<<((int)NF + 255) / 256, 256, 0, stream>>>(bufB, b1, (int)NF, F16, 1);

    // =============== layer 2 (H=16) ===============
    gemm_kernel<0><<<gBig, 256, 0, stream>>>(bufB, W2, nullptr, bufA, N, F16, F16);
    al_kernel<<<(N * NH + 3) / 4, 256, 0, stream>>>(bufA, a2s, a2d, als, ald, N, NH, CH);
    hipMemsetAsync(menc, 0, (size_t)N * NH * 4, stream);
    hipMemsetAsync(den,  0, (size_t)N * NH * 4, stream);
    edge_max_kernel   <<<(nEdgeThreads16 + 255) / 256, 256, 0, stream>>>(als, ald, srcv, dstv, ebuf, menc, E, NH);
    edge_expsum_kernel<<<(nEdgeThreads16 + 255) / 256, 256, 0, stream>>>(ebuf, menc, den, dstv, E, NH);
    hipMemsetAsync(bufB, 0, NF * 4, stream);
    aggregate_kernel<<<E, 256, 0, stream>>>(bufA, ebuf, den, srcv, dstv, bufB, NH, CH);
    bias_act_kernel<<<((int)NF + 255) / 256, 256, 0, stream>>>(bufB, b2, (int)NF, F16, 1);

    // =============== layer 3 (H=1, mean over 1 head == identity) ===============
    dim3 gL3((CH + BN - 1) / BN, (N + BM - 1) / BM);          // (1,79)
    gemm_kernel<0><<<gL3, 256, 0, stream>>>(bufB, W3, nullptr, h3a, N, CH, F16);
    al_kernel<<<(N + 3) / 4, 256, 0, stream>>>(h3a, a3s, a3d, als, ald, N, 1, CH);
    hipMemsetAsync(menc, 0, (size_t)N * 4, stream);
    hipMemsetAsync(den,  0, (size_t)N * 4, stream);
    edge_max_kernel   <<<(E + 255) / 256, 256, 0, stream>>>(als, ald, srcv, dstv, ebuf, menc, E, 1);
    edge_expsum_kernel<<<(E + 255) / 256, 256, 0, stream>>>(ebuf, menc, den, dstv, E, 1);
    hipMemsetAsync(h3b, 0, (size_t)N * CH * 4, stream);
    aggregate_kernel<<<E, 128, 0, stream>>>(h3a, ebuf, den, srcv, dstv, h3b, 1, CH);
    bias_act_kernel<<<(N * CH + 255) / 256, 256, 0, stream>>>(h3b, b3, N * CH, CH, 0);

    // =============== final FC + ReLU: out[N,N] ===============
    dim3 gFC((N + BN - 1) / BN, (N + BM - 1) / BM);           // (79,79)
    gemm_kernel<1><<<gFC, 256, 0, stream>>>(h3b, fcW, fcb, out, N, N, CH);
}

// Round 2
// 1972.883 us; speedup vs baseline: 1.8041x; 1.8041x over previous
//
#include <hip/hip_runtime.h>
#include <hip/hip_bf16.h>
#include <math.h>

#define N_NODES 10000
#define N_EDGES 100000
#define F_IN    128
#define CH      120
#define NH      16
#define NEG_SLOPE 0.2f

typedef unsigned short ushort_t;
typedef short short8 __attribute__((ext_vector_type(8)));
typedef float floatx4 __attribute__((ext_vector_type(4)));

// fp32 -> bf16 (RNE), finite inputs
__device__ inline ushort_t f2b(float f) {
    unsigned u = __float_as_uint(f);
    unsigned r = (u + 0x7fffu + ((u >> 16) & 1u)) >> 16;
    return (ushort_t)r;
}

// ======================== bf16 MFMA GEMM ========================
// C[M,Nn] = A[M,K] @ B[K,Nn] (+bias) (+ReLU).  A,B bf16 bits, C fp32.
// 128x128 tile, BK=32, 4 waves (2x2), each wave 64x64 = 4x4 mfma frags.
#define GBM 128
#define GBN 128
#define GBK 32
#define LDSS 40   // padded row stride (shorts): 80B, 16B-aligned rows, 2-way banks

template<int ACT>  // 0 none, 1 relu
__global__ __launch_bounds__(256) void gemm_bf16_kernel(
    const ushort_t* __restrict__ A, const ushort_t* __restrict__ B,
    const float* __restrict__ bias, float* __restrict__ C,
    int M, int Nn, int K)
{
    __shared__ ushort_t As[GBM * LDSS];
    __shared__ ushort_t Bs[GBN * LDSS];   // stored transposed: [col][k]
    const int t = threadIdx.x;
    const int lane = t & 63;
    const int wid = t >> 6;
    const int wr = wid >> 1, wc = wid & 1;
    const int row0 = blockIdx.y * GBM, col0 = blockIdx.x * GBN;

    const int laneRow = lane & 15;        // frag row (A) / col (B)
    const int laneK   = (lane >> 4) * 8;  // frag k base

    floatx4 acc[4][4];
#pragma unroll
    for (int m = 0; m < 4; ++m)
#pragma unroll
        for (int n = 0; n < 4; ++n)
            acc[m][n] = (floatx4){0.f, 0.f, 0.f, 0.f};

    // B staging mapping: thread -> 2 cols x 8 ks
    const int bcol2 = (t & 63) * 2;
    const int bkblk = t >> 6;             // 0..3

    for (int k0 = 0; k0 < K; k0 += GBK) {
        // ---- stage A: 512 chunks of 8 bf16; chunk c: row=c>>2, kq=(c&3)*8
#pragma unroll
        for (int i = 0; i < 2; ++i) {
            int c = t + i * 256;
            int r = c >> 2, kq = (c & 3) * 8;
            int gr = row0 + r, gk = k0 + kq;
            short8 v = {0, 0, 0, 0, 0, 0, 0, 0};
            if (gr < M) {
                if (gk + 8 <= K) {
                    v = *reinterpret_cast<const short8*>(A + (size_t)gr * K + gk);
                } else {
#pragma unroll
                    for (int j = 0; j < 8; ++j)
                        if (gk + j < K) v[j] = (short)A[(size_t)gr * K + gk + j];
                }
            }
            *reinterpret_cast<short8*>(&As[r * LDSS + kq]) = v;
        }
        // ---- stage B transposed: read [k][col] pairs, write [col][k]
        {
            short8 v0 = {0, 0, 0, 0, 0, 0, 0, 0};
            short8 v1 = {0, 0, 0, 0, 0, 0, 0, 0};
            int gc = col0 + bcol2;
#pragma unroll
            for (int kk = 0; kk < 8; ++kk) {
                int gk = k0 + bkblk * 8 + kk;
                unsigned w = 0;
                if (gk < K) {
                    if (gc + 1 < Nn)
                        w = *reinterpret_cast<const unsigned*>(B + (size_t)gk * Nn + gc);
                    else if (gc < Nn)
                        w = (unsigned)B[(size_t)gk * Nn + gc];
                }
                v0[kk] = (short)(w & 0xffffu);
                v1[kk] = (short)(w >> 16);
            }
            *reinterpret_cast<short8*>(&Bs[bcol2 * LDSS + bkblk * 8]) = v0;
            *reinterpret_cast<short8*>(&Bs[(bcol2 + 1) * LDSS + bkblk * 8]) = v1;
        }
        __syncthreads();

        short8 af[4], bf[4];
#pragma unroll
        for (int m = 0; m < 4; ++m)
            af[m] = *reinterpret_cast<const short8*>(
                &As[(wr * 64 + m * 16 + laneRow) * LDSS + laneK]);
#pragma unroll
        for (int n = 0; n < 4; ++n)
            bf[n] = *reinterpret_cast<const short8*>(
                &Bs[(wc * 64 + n * 16 + laneRow) * LDSS + laneK]);
#pragma unroll
        for (int m = 0; m < 4; ++m)
#pragma unroll
            for (int n = 0; n < 4; ++n)
                acc[m][n] = __builtin_amdgcn_mfma_f32_16x16x32_bf16(
                    af[m], bf[n], acc[m][n], 0, 0, 0);
        __syncthreads();
    }

    // C/D layout: col = lane&15, row = (lane>>4)*4 + j  [m89-verified]
    const int orow = (lane >> 4) * 4;
#pragma unroll
    for (int m = 0; m < 4; ++m) {
#pragma unroll
        for (int n = 0; n < 4; ++n) {
            int gc = col0 + wc * 64 + n * 16 + laneRow;
            if (gc >= Nn) continue;
            float bv = bias ? bias[gc] : 0.f;
#pragma unroll
            for (int j = 0; j < 4; ++j) {
                int gr = row0 + wr * 64 + m * 16 + orow + j;
                if (gr >= M) continue;
                float v = acc[m][n][j] + bv;
                if (ACT == 1) v = fmaxf(v, 0.f);
                C[(size_t)gr * Nn + gc] = v;
            }
        }
    }
}

// ======================== conversions ========================
__global__ void f2b_kernel(const float* __restrict__ in, ushort_t* __restrict__ out, int n)
{
    int i4 = (blockIdx.x * blockDim.x + threadIdx.x) * 4;
    if (i4 + 4 <= n) {
        float4 v = *reinterpret_cast<const float4*>(in + i4);
        ushort_t o0 = f2b(v.x), o1 = f2b(v.y), o2 = f2b(v.z), o3 = f2b(v.w);
        ushort4 o = make_ushort4(o0, o1, o2, o3);
        *reinterpret_cast<ushort4*>(out + i4) = o;
    } else {
        for (; i4 < n; ++i4) out[i4] = f2b(in[i4]);
    }
}

// out_bf16[i] = act(in[i] + b[i % F]); act: 0 none, 1 ELU
__global__ void bias_act_bf16_kernel(const float* __restrict__ in, const float* __restrict__ b,
                                     ushort_t* __restrict__ out, int total, int F, int act)
{
    int i4 = (blockIdx.x * blockDim.x + threadIdx.x) * 4;
    if (i4 >= total) return;
    float4 v = *reinterpret_cast<const float4*>(in + i4);
    const float* bp = b + (i4 % F);
    float4 bb = *reinterpret_cast<const float4*>(bp);
    float a0 = v.x + bb.x, a1 = v.y + bb.y, a2 = v.z + bb.z, a3 = v.w + bb.w;
    if (act == 1) {
        a0 = (a0 > 0.f) ? a0 : expm1f(a0);
        a1 = (a1 > 0.f) ? a1 : expm1f(a1);
        a2 = (a2 > 0.f) ? a2 : expm1f(a2);
        a3 = (a3 > 0.f) ? a3 : expm1f(a3);
    }
    ushort4 o = make_ushort4(f2b(a0), f2b(a1), f2b(a2), f2b(a3));
    *reinterpret_cast<ushort4*>(out + i4) = o;
}

// ======================== edge-index dtype handling ========================
__global__ void detect_kernel(const int* __restrict__ w, int nwords, int* flag)
{
    int i = blockIdx.x * blockDim.x + threadIdx.x;
    int odd = 2 * i + 1;
    if (odd < nwords && w[odd] != 0) atomicOr(flag, 1);
}

__global__ void convert_kernel(const int* __restrict__ w, const int* __restrict__ flag,
                               int* __restrict__ src, int* __restrict__ dst, int E)
{
    int i = blockIdx.x * blockDim.x + threadIdx.x;
    if (i >= E) return;
    if (*flag == 0) {           // int64
        src[i] = w[2 * i];
        dst[i] = w[2 * E + 2 * i];
    } else {                    // int32
        src[i] = w[i];
        dst[i] = w[E + i];
    }
}

// ======================== attention pieces ========================
__global__ void al_kernel(const float* __restrict__ h,
                          const float* __restrict__ a_s, const float* __restrict__ a_d,
                          float* __restrict__ als, float* __restrict__ ald,
                          int Nn, int Hh, int Cc)
{
    int wid  = (blockIdx.x * blockDim.x + threadIdx.x) >> 6;
    int lane = threadIdx.x & 63;
    if (wid >= Nn * Hh) return;
    int n = wid / Hh, hh = wid - n * Hh;
    const float* hp = h + (size_t)n * Hh * Cc + hh * Cc;
    float s1 = 0.f, s2 = 0.f;
    for (int c = lane; c < Cc; c += 64) {
        float v = hp[c];
        s1 += v * a_s[hh * Cc + c];
        s2 += v * a_d[hh * Cc + c];
    }
#pragma unroll
    for (int off = 32; off; off >>= 1) {
        s1 += __shfl_down(s1, off);
        s2 += __shfl_down(s2, off);
    }
    if (lane == 0) { als[wid] = s1; ald[wid] = s2; }
}

__device__ inline unsigned f2enc(float f) {
    unsigned u = __float_as_uint(f);
    return (u & 0x80000000u) ? ~u : (u | 0x80000000u);
}
__device__ inline float enc2f(unsigned k) {
    unsigned u = (k & 0x80000000u) ? (k ^ 0x80000000u) : ~k;
    return __uint_as_float(u);
}

__global__ void edge_max_kernel(const float* __restrict__ als, const float* __restrict__ ald,
                                const int* __restrict__ src, const int* __restrict__ dst,
                                float* __restrict__ ebuf, unsigned* __restrict__ menc,
                                int E, int Hh)
{
    int idx = blockIdx.x * blockDim.x + threadIdx.x;
    if (idx >= E * Hh) return;
    int e = idx / Hh, hh = idx - e * Hh;
    int s = src[e], d = dst[e];
    float v = als[s * Hh + hh] + ald[d * Hh + hh];
    v = (v > 0.f) ? v : NEG_SLOPE * v;
    ebuf[idx] = v;
    atomicMax(menc + d * Hh + hh, f2enc(v));
}

__global__ void edge_expsum_kernel(float* __restrict__ ebuf,
                                   const unsigned* __restrict__ menc,
                                   float* __restrict__ den,
                                   const int* __restrict__ dst, int E, int Hh)
{
    int idx = blockIdx.x * blockDim.x + threadIdx.x;
    if (idx >= E * Hh) return;
    int e = idx / Hh, hh = idx - e * Hh;
    int d = dst[e];
    float m  = enc2f(menc[d * Hh + hh]);
    float ex = expf(ebuf[idx] - m);
    ebuf[idx] = ex;
    atomicAdd(den + d * Hh + hh, ex);
}

__global__ void aggregate_kernel(const float* __restrict__ h,
                                 const float* __restrict__ ebuf, const float* __restrict__ den,
                                 const int* __restrict__ src, const int* __restrict__ dst,
                                 float* __restrict__ outp, int Hh, int Cc)
{
    __shared__ float alpha[NH];
    int e = blockIdx.x;
    int s = src[e], d = dst[e];
    int F = Hh * Cc;
    if ((int)threadIdx.x < Hh)
        alpha[threadIdx.x] = ebuf[(size_t)e * Hh + threadIdx.x] / den[d * Hh + threadIdx.x];
    __syncthreads();
    const float* hp = h + (size_t)s * F;
    float* op = outp + (size_t)d * F;
    for (int i = threadIdx.x; i < F; i += blockDim.x)
        atomicAdd(op + i, hp[i] * alpha[i / CH]);
}

// ======================== launch ========================
extern "C" void kernel_launch(void* const* d_in, const int* in_sizes, int n_in,
                              void* d_out, int out_size, void* d_ws, size_t ws_size,
                              hipStream_t stream)
{
    const float* x   = (const float*)d_in[0];
    const int*   ei  = (const int*)  d_in[1];
    const float* W1  = (const float*)d_in[2];
    const float* a1s = (const float*)d_in[3];
    const float* a1d = (const float*)d_in[4];
    const float* b1  = (const float*)d_in[5];
    const float* W2  = (const float*)d_in[6];
    const float* a2s = (const float*)d_in[7];
    const float* a2d = (const float*)d_in[8];
    const float* b2  = (const float*)d_in[9];
    const float* W3  = (const float*)d_in[10];
    const float* a3s = (const float*)d_in[11];
    const float* a3d = (const float*)d_in[12];
    const float* b3  = (const float*)d_in[13];
    const float* fcW = (const float*)d_in[14];
    const float* fcb = (const float*)d_in[15];

    float* out = (float*)d_out;
    const int N = N_NODES, E = N_EDGES;
    const int F16 = NH * CH;                 // 1920
    const size_t NF = (size_t)N * F16;       // 19.2M

    // ---- scratch layout inside d_out (400MB; FC overwrites all of it last)
    float*    bufA = out;                               // GEMM out fp32
    float*    bufB = bufA + NF;                         // aggregated fp32
    ushort_t* hb   = (ushort_t*)(bufB + NF);            // activated bf16 [N,F16]
    ushort_t* xb   = hb + NF;                           // x bf16
    ushort_t* W1b  = xb + (size_t)N * F_IN;
    ushort_t* W2b  = W1b + (size_t)F_IN * F16;
    ushort_t* W3b  = W2b + (size_t)F16 * F16;
    float*    h3a  = (float*)(W3b + (size_t)F16 * CH);  // layer3 GEMM out
    float*    als  = h3a + (size_t)N * CH;
    float*    ald  = als + (size_t)N * NH;
    unsigned* menc = (unsigned*)(ald + (size_t)N * NH);
    float*    den  = (float*)(menc + (size_t)N * NH);
    float*    ebuf = den + (size_t)N * NH;
    int*      srcv = (int*)(ebuf + (size_t)E * NH);
    int*      dstv = srcv + E;
    int*      flag = dstv + E;
    // ---- d_ws: FC inputs (must not alias d_out)
    ushort_t* h3bb = (ushort_t*)d_ws;                   // [N,CH] bf16
    ushort_t* fcWb = h3bb + (size_t)N * CH;             // [CH,N] bf16

    // ---- edge decode
    hipMemsetAsync(flag, 0, sizeof(int), stream);
    detect_kernel <<<(E + 255) / 256, 256, 0, stream>>>(ei, 2 * E, flag);
    convert_kernel<<<(E + 255) / 256, 256, 0, stream>>>(ei, flag, srcv, dstv, E);

    // ---- bf16 conversions (weights + x)
    f2b_kernel<<<(N * F_IN / 4 + 255) / 256, 256, 0, stream>>>(x, xb, N * F_IN);
    f2b_kernel<<<(F_IN * F16 / 4 + 255) / 256, 256, 0, stream>>>(W1, W1b, F_IN * F16);
    f2b_kernel<<<(F16 * F16 / 4 + 255) / 256, 256, 0, stream>>>(W2, W2b, F16 * F16);
    f2b_kernel<<<(F16 * CH / 4 + 255) / 256, 256, 0, stream>>>(W3, W3b, F16 * CH);
    f2b_kernel<<<(CH * N / 4 + 255) / 256, 256, 0, stream>>>(fcW, fcWb, CH * N);

    dim3 gBig(F16 / GBN, (N + GBM - 1) / GBM);          // (15,79)
    int nET16 = E * NH;

    // =============== layer 1 ===============
    gemm_bf16_kernel<0><<<gBig, 256, 0, stream>>>(xb, W1b, nullptr, bufA, N, F16, F_IN);
    al_kernel<<<(N * NH + 3) / 4, 256, 0, stream>>>(bufA, a1s, a1d, als, ald, N, NH, CH);
    hipMemsetAsync(menc, 0, (size_t)N * NH * 4, stream);
    hipMemsetAsync(den,  0, (size_t)N * NH * 4, stream);
    edge_max_kernel   <<<(nET16 + 255) / 256, 256, 0, stream>>>(als, ald, srcv, dstv, ebuf, menc, E, NH);
    edge_expsum_kernel<<<(nET16 + 255) / 256, 256, 0, stream>>>(ebuf, menc, den, dstv, E, NH);
    hipMemsetAsync(bufB, 0, NF * 4, stream);
    aggregate_kernel<<<E, 256, 0, stream>>>(bufA, ebuf, den, srcv, dstv, bufB, NH, CH);
    bias_act_bf16_kernel<<<((int)NF / 4 + 255) / 256, 256, 0, stream>>>(bufB, b1, hb, (int)NF, F16, 1);

    // =============== layer 2 ===============
    gemm_bf16_kernel<0><<<gBig, 256, 0, stream>>>(hb, W2b, nullptr, bufA, N, F16, F16);
    al_kernel<<<(N * NH + 3) / 4, 256, 0, stream>>>(bufA, a2s, a2d, als, ald, N, NH, CH);
    hipMemsetAsync(menc, 0, (size_t)N * NH * 4, stream);
    hipMemsetAsync(den,  0, (size_t)N * NH * 4, stream);
    edge_max_kernel   <<<(nET16 + 255) / 256, 256, 0, stream>>>(als, ald, srcv, dstv, ebuf, menc, E, NH);
    edge_expsum_kernel<<<(nET16 + 255) / 256, 256, 0, stream>>>(ebuf, menc, den, dstv, E, NH);
    hipMemsetAsync(bufB, 0, NF * 4, stream);
    aggregate_kernel<<<E, 256, 0, stream>>>(bufA, ebuf, den, srcv, dstv, bufB, NH, CH);
    bias_act_bf16_kernel<<<((int)NF / 4 + 255) / 256, 256, 0, stream>>>(bufB, b2, hb, (int)NF, F16, 1);

    // =============== layer 3 (H=1) ===============
    dim3 gL3(1, (N + GBM - 1) / GBM);
    gemm_bf16_kernel<0><<<gL3, 256, 0, stream>>>(hb, W3b, nullptr, h3a, N, CH, F16);
    al_kernel<<<(N + 3) / 4, 256, 0, stream>>>(h3a, a3s, a3d, als, ald, N, 1, CH);
    hipMemsetAsync(menc, 0, (size_t)N * 4, stream);
    hipMemsetAsync(den,  0, (size_t)N * 4, stream);
    edge_max_kernel   <<<(E + 255) / 256, 256, 0, stream>>>(als, ald, srcv, dstv, ebuf, menc, E, 1);
    edge_expsum_kernel<<<(E + 255) / 256, 256, 0, stream>>>(ebuf, menc, den, dstv, E, 1);
    hipMemsetAsync(bufB, 0, (size_t)N * CH * 4, stream);
    aggregate_kernel<<<E, 128, 0, stream>>>(h3a, ebuf, den, srcv, dstv, bufB, 1, CH);
    bias_act_bf16_kernel<<<(N * CH / 4 + 255) / 256, 256, 0, stream>>>(bufB, b3, h3bb, N * CH, CH, 0);

    // =============== FC + ReLU ===============
    dim3 gFC((N + GBN - 1) / GBN, (N + GBM - 1) / GBM);  // (79,79)
    gemm_bf16_kernel<1><<<gFC, 256, 0, stream>>>(h3bb, fcWb, fcb, out, N, N, CH);
}

// Round 3
// 864.454 us; speedup vs baseline: 4.1173x; 2.2822x over previous
//
#include <hip/hip_runtime.h>
#include <hip/hip_bf16.h>
#include <math.h>

#define N_NODES 10000
#define N_EDGES 100000
#define F_IN    128
#define CH      120
#define NH      16
#define NEG_SLOPE 0.2f

typedef unsigned short ushort_t;
typedef short short8 __attribute__((ext_vector_type(8)));
typedef float floatx4 __attribute__((ext_vector_type(4)));

__device__ inline ushort_t f2b(float f) {            // fp32->bf16 RNE
    unsigned u = __float_as_uint(f);
    unsigned r = (u + 0x7fffu + ((u >> 16) & 1u)) >> 16;
    return (ushort_t)r;
}
__device__ inline float b2f(ushort_t u) { return __uint_as_float(((unsigned)u) << 16); }

// ======================== bf16 MFMA GEMM ========================
// 128x128 tile, BK=32, 4 waves (2x2), wave = 64x64 via 4x4 16x16x32 frags.
#define GBM 128
#define GBN 128
#define GBK 32
#define LDSS 40

template<int ACT, int OUTBF>   // ACT: 0 none 1 relu; OUTBF: output bf16?
__global__ __launch_bounds__(256) void gemm_bf16_kernel(
    const ushort_t* __restrict__ A, const ushort_t* __restrict__ B,
    const float* __restrict__ bias, void* __restrict__ Cv,
    int M, int Nn, int K)
{
    __shared__ ushort_t As[GBM * LDSS];
    __shared__ ushort_t Bs[GBN * LDSS];   // transposed: [col][k]
    const int t = threadIdx.x;
    const int lane = t & 63;
    const int wid = t >> 6;
    const int wr = wid >> 1, wc = wid & 1;
    const int row0 = blockIdx.y * GBM, col0 = blockIdx.x * GBN;
    const int laneRow = lane & 15;
    const int laneK   = (lane >> 4) * 8;

    floatx4 acc[4][4];
#pragma unroll
    for (int m = 0; m < 4; ++m)
#pragma unroll
        for (int n = 0; n < 4; ++n)
            acc[m][n] = (floatx4){0.f, 0.f, 0.f, 0.f};

    const int bcol2 = (t & 63) * 2;
    const int bkblk = t >> 6;

    for (int k0 = 0; k0 < K; k0 += GBK) {
#pragma unroll
        for (int i = 0; i < 2; ++i) {            // stage A (128x32)
            int c = t + i * 256;
            int r = c >> 2, kq = (c & 3) * 8;
            int gr = row0 + r, gk = k0 + kq;
            short8 v = {0, 0, 0, 0, 0, 0, 0, 0};
            if (gr < M) {
                if (gk + 8 <= K) {
                    v = *reinterpret_cast<const short8*>(A + (size_t)gr * K + gk);
                } else {
#pragma unroll
                    for (int j = 0; j < 8; ++j)
                        if (gk + j < K) v[j] = (short)A[(size_t)gr * K + gk + j];
                }
            }
            *reinterpret_cast<short8*>(&As[r * LDSS + kq]) = v;
        }
        {                                        // stage B transposed (32x128)
            short8 v0 = {0, 0, 0, 0, 0, 0, 0, 0};
            short8 v1 = {0, 0, 0, 0, 0, 0, 0, 0};
            int gc = col0 + bcol2;
#pragma unroll
            for (int kk = 0; kk < 8; ++kk) {
                int gk = k0 + bkblk * 8 + kk;
                unsigned w = 0;
                if (gk < K) {
                    if (gc + 1 < Nn)
                        w = *reinterpret_cast<const unsigned*>(B + (size_t)gk * Nn + gc);
                    else if (gc < Nn)
                        w = (unsigned)B[(size_t)gk * Nn + gc];
                }
                v0[kk] = (short)(w & 0xffffu);
                v1[kk] = (short)(w >> 16);
            }
            *reinterpret_cast<short8*>(&Bs[bcol2 * LDSS + bkblk * 8]) = v0;
            *reinterpret_cast<short8*>(&Bs[(bcol2 + 1) * LDSS + bkblk * 8]) = v1;
        }
        __syncthreads();

        short8 af[4], bf[4];
#pragma unroll
        for (int m = 0; m < 4; ++m)
            af[m] = *reinterpret_cast<const short8*>(
                &As[(wr * 64 + m * 16 + laneRow) * LDSS + laneK]);
#pragma unroll
        for (int n = 0; n < 4; ++n)
            bf[n] = *reinterpret_cast<const short8*>(
                &Bs[(wc * 64 + n * 16 + laneRow) * LDSS + laneK]);
#pragma unroll
        for (int m = 0; m < 4; ++m)
#pragma unroll
            for (int n = 0; n < 4; ++n)
                acc[m][n] = __builtin_amdgcn_mfma_f32_16x16x32_bf16(
                    af[m], bf[n], acc[m][n], 0, 0, 0);
        __syncthreads();
    }

    const int orow = (lane >> 4) * 4;   // C/D: col=lane&15, row=(lane>>4)*4+j
#pragma unroll
    for (int m = 0; m < 4; ++m) {
#pragma unroll
        for (int n = 0; n < 4; ++n) {
            int gc = col0 + wc * 64 + n * 16 + laneRow;
            if (gc >= Nn) continue;
            float bv = bias ? bias[gc] : 0.f;
#pragma unroll
            for (int j = 0; j < 4; ++j) {
                int gr = row0 + wr * 64 + m * 16 + orow + j;
                if (gr >= M) continue;
                float v = acc[m][n][j] + bv;
                if (ACT == 1) v = fmaxf(v, 0.f);
                if (OUTBF) ((ushort_t*)Cv)[(size_t)gr * Nn + gc] = f2b(v);
                else       ((float*)Cv)   [(size_t)gr * Nn + gc] = v;
            }
        }
    }
}

// ======================== conversions ========================
__global__ void f2b_kernel(const float* __restrict__ in, ushort_t* __restrict__ out, int n)
{
    int i4 = (blockIdx.x * blockDim.x + threadIdx.x) * 4;
    if (i4 + 4 <= n) {
        float4 v = *reinterpret_cast<const float4*>(in + i4);
        ushort4 o = make_ushort4(f2b(v.x), f2b(v.y), f2b(v.z), f2b(v.w));
        *reinterpret_cast<ushort4*>(out + i4) = o;
    } else {
        for (; i4 < n; ++i4) out[i4] = f2b(in[i4]);
    }
}

// ======================== edge-index dtype handling ========================
__global__ void detect_kernel(const int* __restrict__ w, int nwords, int* flag)
{
    int i = blockIdx.x * blockDim.x + threadIdx.x;
    int odd = 2 * i + 1;
    if (odd < nwords && w[odd] != 0) atomicOr(flag, 1);
}

__global__ void convert_kernel(const int* __restrict__ w, const int* __restrict__ flag,
                               int* __restrict__ src, int* __restrict__ dst, int E)
{
    int i = blockIdx.x * blockDim.x + threadIdx.x;
    if (i >= E) return;
    if (*flag == 0) { src[i] = w[2 * i]; dst[i] = w[2 * E + 2 * i]; }
    else            { src[i] = w[i];     dst[i] = w[E + i]; }
}

// ======================== CSR build (counting sort by dst) ========================
__global__ void hist_kernel(const int* __restrict__ dst, int* __restrict__ deg, int E)
{
    int i = blockIdx.x * blockDim.x + threadIdx.x;
    if (i < E) atomicAdd(deg + dst[i], 1);
}

#define SCAN_T 1024
__global__ __launch_bounds__(SCAN_T) void scan_kernel(
    const int* __restrict__ deg, int* __restrict__ off, int n)
{
    __shared__ int part[SCAN_T];
    int t = threadIdx.x;
    int per = (n + SCAN_T - 1) / SCAN_T;
    int b0 = t * per, b1 = min(b0 + per, n);
    int s = 0;
    for (int i = b0; i < b1; ++i) s += deg[i];
    part[t] = s;
    __syncthreads();
    for (int d = 1; d < SCAN_T; d <<= 1) {
        int v = (t >= d) ? part[t - d] : 0;
        __syncthreads();
        part[t] += v;
        __syncthreads();
    }
    int run = (t == 0) ? 0 : part[t - 1];
    for (int i = b0; i < b1; ++i) { off[i] = run; run += deg[i]; }
    if (t == SCAN_T - 1) off[n] = run;
}

__global__ void scatter_kernel(const int* __restrict__ dst, const int* __restrict__ off,
                               int* __restrict__ cnt, int* __restrict__ perm, int E)
{
    int i = blockIdx.x * blockDim.x + threadIdx.x;
    if (i >= E) return;
    int d = dst[i];
    int pos = off[d] + atomicAdd(cnt + d, 1);
    perm[pos] = i;
}

// ======================== attention pieces ========================
// al_src[n,h] = sum_c h[n,h,c]*a_s[h,c]; h is bf16. One wave per (n,h).
__global__ void al_bf16_kernel(const ushort_t* __restrict__ h,
                               const float* __restrict__ a_s, const float* __restrict__ a_d,
                               float* __restrict__ als, float* __restrict__ ald,
                               int Nn, int Hh, int Cc)
{
    int wid  = (blockIdx.x * blockDim.x + threadIdx.x) >> 6;
    int lane = threadIdx.x & 63;
    if (wid >= Nn * Hh) return;
    int n = wid / Hh, hh = wid - n * Hh;
    const ushort_t* hp = h + (size_t)n * Hh * Cc + hh * Cc;
    float s1 = 0.f, s2 = 0.f;
    int c = lane * 2;
    if (c < Cc) {
        unsigned w = *reinterpret_cast<const unsigned*>(hp + c);
        float f0 = b2f((ushort_t)(w & 0xffffu)), f1 = b2f((ushort_t)(w >> 16));
        float2 as2 = *reinterpret_cast<const float2*>(a_s + hh * Cc + c);
        float2 ad2 = *reinterpret_cast<const float2*>(a_d + hh * Cc + c);
        s1 = f0 * as2.x + f1 * as2.y;
        s2 = f0 * ad2.x + f1 * ad2.y;
    }
#pragma unroll
    for (int offp = 32; offp; offp >>= 1) {
        s1 += __shfl_down(s1, offp);
        s2 += __shfl_down(s2, offp);
    }
    if (lane == 0) { als[wid] = s1; ald[wid] = s2; }
}

__device__ inline unsigned f2enc(float f) {
    unsigned u = __float_as_uint(f);
    return (u & 0x80000000u) ? ~u : (u | 0x80000000u);
}
__device__ inline float enc2f(unsigned k) {
    unsigned u = (k & 0x80000000u) ? (k ^ 0x80000000u) : ~k;
    return __uint_as_float(u);
}

__global__ void edge_max_kernel(const float* __restrict__ als, const float* __restrict__ ald,
                                const int* __restrict__ src, const int* __restrict__ dst,
                                float* __restrict__ ebuf, unsigned* __restrict__ menc,
                                int E, int Hh)
{
    int idx = blockIdx.x * blockDim.x + threadIdx.x;
    if (idx >= E * Hh) return;
    int e = idx / Hh, hh = idx - e * Hh;
    int s = src[e], d = dst[e];
    float v = als[s * Hh + hh] + ald[d * Hh + hh];
    v = (v > 0.f) ? v : NEG_SLOPE * v;
    ebuf[idx] = v;
    atomicMax(menc + d * Hh + hh, f2enc(v));
}

__global__ void edge_expsum_kernel(float* __restrict__ ebuf,
                                   const unsigned* __restrict__ menc,
                                   float* __restrict__ den,
                                   const int* __restrict__ dst, int E, int Hh)
{
    int idx = blockIdx.x * blockDim.x + threadIdx.x;
    if (idx >= E * Hh) return;
    int e = idx / Hh, hh = idx - e * Hh;
    int d = dst[e];
    float m  = enc2f(menc[d * Hh + hh]);
    float ex = __expf(ebuf[idx] - m);
    ebuf[idx] = ex;
    atomicAdd(den + d * Hh + hh, ex);
}

// ======================== CSR aggregation (fused bias+act+bf16 out) ========================
// One block per dst node. out[d] = act( sum_e alpha_e * h[src_e] + bias ), bf16.
#define AGG_CHUNK 8
__global__ void agg_csr_kernel(const ushort_t* __restrict__ h,
                               const float* __restrict__ ebuf, const float* __restrict__ den,
                               const int* __restrict__ off, const int* __restrict__ perm,
                               const int* __restrict__ srcv,
                               const float* __restrict__ bias,
                               ushort_t* __restrict__ outb,
                               int Hh, int F, int act)
{
    const int d = blockIdx.x;
    const int t = threadIdx.x;
    __shared__ float rden[NH];
    __shared__ float alphaL[AGG_CHUNK][NH];
    __shared__ int   srcL[AGG_CHUNK];
    if (t < Hh) rden[t] = 1.f / den[d * Hh + t];
    const int start = off[d], end = off[d + 1];
    const int nact = F >> 3;            // threads doing accumulation
    const int head = (t * 8) / CH;      // each 8-elem chunk stays in one head (120%8==0)
    float acc[8] = {0.f, 0.f, 0.f, 0.f, 0.f, 0.f, 0.f, 0.f};
    __syncthreads();
    for (int base = start; base < end; base += AGG_CHUNK) {
        int nb = min(AGG_CHUNK, end - base);
        if (t < nb) srcL[t] = srcv[perm[base + t]];
        if (t < nb * Hh) {
            int j = t / Hh, hh = t - j * Hh;
            alphaL[j][hh] = ebuf[(size_t)perm[base + j] * Hh + hh] * rden[hh];
        }
        __syncthreads();
        if (t < nact) {
            for (int j = 0; j < nb; ++j) {
                int s = srcL[j];
                float a = alphaL[j][head];
                short8 v = *reinterpret_cast<const short8*>(h + (size_t)s * F + t * 8);
#pragma unroll
                for (int k = 0; k < 8; ++k)
                    acc[k] = fmaf(b2f((ushort_t)v[k]), a, acc[k]);
            }
        }
        __syncthreads();
    }
    if (t < nact) {
        short8 o;
#pragma unroll
        for (int k = 0; k < 8; ++k) {
            float v = acc[k] + bias[t * 8 + k];
            if (act) v = (v > 0.f) ? v : expm1f(v);
            o[k] = (short)f2b(v);
        }
        *reinterpret_cast<short8*>(outb + (size_t)d * F + t * 8) = o;
    }
}

// ======================== launch ========================
extern "C" void kernel_launch(void* const* d_in, const int* in_sizes, int n_in,
                              void* d_out, int out_size, void* d_ws, size_t ws_size,
                              hipStream_t stream)
{
    const float* x   = (const float*)d_in[0];
    const int*   ei  = (const int*)  d_in[1];
    const float* W1  = (const float*)d_in[2];
    const float* a1s = (const float*)d_in[3];
    const float* a1d = (const float*)d_in[4];
    const float* b1  = (const float*)d_in[5];
    const float* W2  = (const float*)d_in[6];
    const float* a2s = (const float*)d_in[7];
    const float* a2d = (const float*)d_in[8];
    const float* b2  = (const float*)d_in[9];
    const float* W3  = (const float*)d_in[10];
    const float* a3s = (const float*)d_in[11];
    const float* a3d = (const float*)d_in[12];
    const float* b3  = (const float*)d_in[13];
    const float* fcW = (const float*)d_in[14];
    const float* fcb = (const float*)d_in[15];

    float* out = (float*)d_out;
    const int N = N_NODES, E = N_EDGES;
    const int F16 = NH * CH;                 // 1920
    const size_t NF = (size_t)N * F16;

    // ---- scratch inside d_out (FC overwrites all of d_out last; FC inputs in d_ws)
    ushort_t* hraw = (ushort_t*)out;                    // GEMM out bf16 [N,F16]
    ushort_t* hagg = hraw + NF;                         // aggregated bf16 [N,F16]
    ushort_t* xb   = hagg + NF;
    ushort_t* W1b  = xb   + (size_t)N * F_IN;
    ushort_t* W2b  = W1b  + (size_t)F_IN * F16;
    ushort_t* W3b  = W2b  + (size_t)F16 * F16;
    ushort_t* h3raw= W3b  + (size_t)F16 * CH;           // [N,CH]
    float*    als  = (float*)(h3raw + (size_t)N * CH);
    float*    ald  = als + (size_t)N * NH;
    unsigned* menc = (unsigned*)(ald + (size_t)N * NH);
    float*    den  = (float*)(menc + (size_t)N * NH);
    float*    ebuf = den + (size_t)N * NH;              // [E,NH]
    int*      srcv = (int*)(ebuf + (size_t)E * NH);
    int*      dstv = srcv + E;
    int*      flag = dstv + E;
    int*      deg  = flag + 1;                          // [N]
    int*      offv = deg + N;                           // [N+1]
    int*      cnt  = offv + N + 1;                      // [N]
    int*      perm = cnt + N;                           // [E]
    // ---- d_ws: FC inputs
    ushort_t* h3bb = (ushort_t*)d_ws;                   // [N,CH]
    ushort_t* fcWb = h3bb + (size_t)N * CH;             // [CH,N]

    // ---- edge decode + CSR build (shared by all 3 layers)
    hipMemsetAsync(flag, 0, sizeof(int), stream);
    detect_kernel <<<(E + 255) / 256, 256, 0, stream>>>(ei, 2 * E, flag);
    convert_kernel<<<(E + 255) / 256, 256, 0, stream>>>(ei, flag, srcv, dstv, E);
    hipMemsetAsync(deg, 0, (size_t)N * 4, stream);
    hipMemsetAsync(cnt, 0, (size_t)N * 4, stream);
    hist_kernel   <<<(E + 255) / 256, 256, 0, stream>>>(dstv, deg, E);
    scan_kernel   <<<1, SCAN_T, 0, stream>>>(deg, offv, N);
    scatter_kernel<<<(E + 255) / 256, 256, 0, stream>>>(dstv, offv, cnt, perm, E);

    // ---- bf16 conversions
    f2b_kernel<<<(N * F_IN / 4 + 255) / 256, 256, 0, stream>>>(x, xb, N * F_IN);
    f2b_kernel<<<(F_IN * F16 / 4 + 255) / 256, 256, 0, stream>>>(W1, W1b, F_IN * F16);
    f2b_kernel<<<(F16 * F16 / 4 + 255) / 256, 256, 0, stream>>>(W2, W2b, F16 * F16);
    f2b_kernel<<<(F16 * CH / 4 + 255) / 256, 256, 0, stream>>>(W3, W3b, F16 * CH);
    f2b_kernel<<<(CH * N / 4 + 255) / 256, 256, 0, stream>>>(fcW, fcWb, CH * N);

    dim3 gBig(F16 / GBN, (N + GBM - 1) / GBM);
    int nET16 = E * NH;

    // =============== layer 1 ===============
    gemm_bf16_kernel<0, 1><<<gBig, 256, 0, stream>>>(xb, W1b, nullptr, hraw, N, F16, F_IN);
    al_bf16_kernel<<<(N * NH + 3) / 4, 256, 0, stream>>>(hraw, a1s, a1d, als, ald, N, NH, CH);
    hipMemsetAsync(menc, 0, (size_t)N * NH * 4, stream);
    hipMemsetAsync(den,  0, (size_t)N * NH * 4, stream);
    edge_max_kernel   <<<(nET16 + 255) / 256, 256, 0, stream>>>(als, ald, srcv, dstv, ebuf, menc, E, NH);
    edge_expsum_kernel<<<(nET16 + 255) / 256, 256, 0, stream>>>(ebuf, menc, den, dstv, E, NH);
    agg_csr_kernel<<<N, 256, 0, stream>>>(hraw, ebuf, den, offv, perm, srcv, b1, hagg, NH, F16, 1);

    // =============== layer 2 ===============
    gemm_bf16_kernel<0, 1><<<gBig, 256, 0, stream>>>(hagg, W2b, nullptr, hraw, N, F16, F16);
    al_bf16_kernel<<<(N * NH + 3) / 4, 256, 0, stream>>>(hraw, a2s, a2d, als, ald, N, NH, CH);
    hipMemsetAsync(menc, 0, (size_t)N * NH * 4, stream);
    hipMemsetAsync(den,  0, (size_t)N * NH * 4, stream);
    edge_max_kernel   <<<(nET16 + 255) / 256, 256, 0, stream>>>(als, ald, srcv, dstv, ebuf, menc, E, NH);
    edge_expsum_kernel<<<(nET16 + 255) / 256, 256, 0, stream>>>(ebuf, menc, den, dstv, E, NH);
    agg_csr_kernel<<<N, 256, 0, stream>>>(hraw, ebuf, den, offv, perm, srcv, b2, hagg, NH, F16, 1);

    // =============== layer 3 (H=1) ===============
    dim3 gL3(1, (N + GBM - 1) / GBM);
    gemm_bf16_kernel<0, 1><<<gL3, 256, 0, stream>>>(hagg, W3b, nullptr, h3raw, N, CH, F16);
    al_bf16_kernel<<<(N + 3) / 4, 256, 0, stream>>>(h3raw, a3s, a3d, als, ald, N, 1, CH);
    hipMemsetAsync(menc, 0, (size_t)N * 4, stream);
    hipMemsetAsync(den,  0, (size_t)N * 4, stream);
    edge_max_kernel   <<<(E + 255) / 256, 256, 0, stream>>>(als, ald, srcv, dstv, ebuf, menc, E, 1);
    edge_expsum_kernel<<<(E + 255) / 256, 256, 0, stream>>>(ebuf, menc, den, dstv, E, 1);
    agg_csr_kernel<<<N, 64, 0, stream>>>(h3raw, ebuf, den, offv, perm, srcv, b3, h3bb, 1, CH, 0);

    // =============== FC + ReLU ===============
    dim3 gFC((N + GBN - 1) / GBN, (N + GBM - 1) / GBM);
    gemm_bf16_kernel<1, 0><<<gFC, 256, 0, stream>>>(h3bb, fcWb, fcb, out, N, N, CH);
}

// Round 4
// 667.476 us; speedup vs baseline: 5.3323x; 1.2951x over previous
//
#include <hip/hip_runtime.h>
#include <hip/hip_bf16.h>
#include <math.h>

#define N_NODES 10000
#define N_EDGES 100000
#define F_IN    128
#define CH      120
#define NH      16
#define NEG_SLOPE 0.2f
#define MPAD    10112          // N padded to multiple of 128

typedef unsigned short ushort_t;
typedef short short8 __attribute__((ext_vector_type(8)));
typedef float floatx4 __attribute__((ext_vector_type(4)));

__device__ inline ushort_t f2b(float f) {            // fp32->bf16 RNE
    unsigned u = __float_as_uint(f);
    unsigned r = (u + 0x7fffu + ((u >> 16) & 1u)) >> 16;
    return (ushort_t)r;
}
__device__ inline float b2f(ushort_t u) { return __uint_as_float(((unsigned)u) << 16); }

// async global->LDS, 16B per lane (dest = wave-uniform base + lane*16)
__device__ __forceinline__ void gload16(const ushort_t* g, ushort_t* l) {
    __builtin_amdgcn_global_load_lds(
        (const __attribute__((address_space(1))) unsigned int*)g,
        (__attribute__((address_space(3))) unsigned int*)l,
        16, 0, 0);
}

// ======================== bf16 MFMA GEMM (m97 structure) ========================
// C[M,Nn] = A[M,K] @ Bt[Nn,K]^T. A stride K, Bt stride K; K multiple of 32.
// Staging buffers padded so no guards needed; C-write guarded by M/Nn.
#define GBM 128
#define GBN 128
#define GBK 32

template<int ACT, int OUTBF>   // ACT: 0 none 1 relu; OUTBF: bf16 out?
__global__ __launch_bounds__(256) void gemm_mfma_kernel(
    const ushort_t* __restrict__ A, const ushort_t* __restrict__ Bt,
    const float* __restrict__ bias, void* __restrict__ Cv,
    int M, int Nn, int K)
{
    __shared__ ushort_t As[GBM * GBK];   // linear [row][k], 8KB
    __shared__ ushort_t Bs[GBN * GBK];   // linear [col][k], 8KB
    const int t = threadIdx.x;
    const int lane = t & 63;
    const int wid = t >> 6;
    const int wr = wid >> 1, wc = wid & 1;
    const int row0 = blockIdx.y * GBM, col0 = blockIdx.x * GBN;
    const int laneRow = lane & 15;
    const int laneK   = (lane >> 4) * 8;
    const int srow = lane >> 2;          // staging: 16 rows per wave-issue
    const int skq  = (lane & 3) * 8;     // staging: k offset

    floatx4 acc[4][4];
#pragma unroll
    for (int m = 0; m < 4; ++m)
#pragma unroll
        for (int n = 0; n < 4; ++n)
            acc[m][n] = (floatx4){0.f, 0.f, 0.f, 0.f};

    for (int k0 = 0; k0 < K; k0 += GBK) {
#pragma unroll
        for (int i = 0; i < 2; ++i) {
            int ai = wid * 2 + i;        // 0..7: 16-row slab of A tile
            gload16(A + (size_t)(row0 + ai * 16 + srow) * K + k0 + skq,
                    &As[ai * 512]);
        }
#pragma unroll
        for (int i = 0; i < 2; ++i) {
            int bi = wid * 2 + i;        // 16-col slab of B tile
            gload16(Bt + (size_t)(col0 + bi * 16 + srow) * K + k0 + skq,
                    &Bs[bi * 512]);
        }
        __syncthreads();

        short8 af[4], bf[4];
#pragma unroll
        for (int m = 0; m < 4; ++m)
            af[m] = *reinterpret_cast<const short8*>(
                &As[(wr * 64 + m * 16 + laneRow) * GBK + laneK]);
#pragma unroll
        for (int n = 0; n < 4; ++n)
            bf[n] = *reinterpret_cast<const short8*>(
                &Bs[(wc * 64 + n * 16 + laneRow) * GBK + laneK]);
#pragma unroll
        for (int m = 0; m < 4; ++m)
#pragma unroll
            for (int n = 0; n < 4; ++n)
                acc[m][n] = __builtin_amdgcn_mfma_f32_16x16x32_bf16(
                    af[m], bf[n], acc[m][n], 0, 0, 0);
        __syncthreads();
    }

    const int orow = (lane >> 4) * 4;   // C/D: col=lane&15, row=(lane>>4)*4+j
#pragma unroll
    for (int m = 0; m < 4; ++m) {
#pragma unroll
        for (int n = 0; n < 4; ++n) {
            int gc = col0 + wc * 64 + n * 16 + laneRow;
            if (gc >= Nn) continue;
            float bv = bias ? bias[gc] : 0.f;
#pragma unroll
            for (int j = 0; j < 4; ++j) {
                int gr = row0 + wr * 64 + m * 16 + orow + j;
                if (gr >= M) continue;
                float v = acc[m][n][j] + bv;
                if (ACT == 1) v = fmaxf(v, 0.f);
                if (OUTBF) ((ushort_t*)Cv)[(size_t)gr * Nn + gc] = f2b(v);
                else       ((float*)Cv)   [(size_t)gr * Nn + gc] = v;
            }
        }
    }
}

// ======================== transpose + f32->bf16 ========================
// out[Npad][Kpad] = in[k][n] (bf16), zero-padded. in: [R][Cc] f32.
__global__ __launch_bounds__(256) void transpose_b_kernel(
    const float* __restrict__ in, ushort_t* __restrict__ out,
    int R, int Cc, int Kpad)
{
    __shared__ float tile[32][33];
    const int tx = threadIdx.x & 31, ty = threadIdx.x >> 5;  // 32x8
    const int k0 = blockIdx.x * 32, n0 = blockIdx.y * 32;
#pragma unroll
    for (int i = 0; i < 4; ++i) {
        int r = k0 + ty + i * 8, c = n0 + tx;
        tile[ty + i * 8][tx] = (r < R && c < Cc) ? in[(size_t)r * Cc + c] : 0.f;
    }
    __syncthreads();
#pragma unroll
    for (int i = 0; i < 4; ++i) {
        int orow = n0 + ty + i * 8, ocol = k0 + tx;
        out[(size_t)orow * Kpad + ocol] = f2b(tile[tx][ty + i * 8]);
    }
}

// ======================== conversions ========================
__global__ void f2b_kernel(const float* __restrict__ in, ushort_t* __restrict__ out, int n)
{
    int i4 = (blockIdx.x * blockDim.x + threadIdx.x) * 4;
    if (i4 + 4 <= n) {
        float4 v = *reinterpret_cast<const float4*>(in + i4);
        ushort4 o = make_ushort4(f2b(v.x), f2b(v.y), f2b(v.z), f2b(v.w));
        *reinterpret_cast<ushort4*>(out + i4) = o;
    } else {
        for (; i4 < n; ++i4) out[i4] = f2b(in[i4]);
    }
}

// ======================== edge-index dtype handling ========================
__global__ void detect_kernel(const int* __restrict__ w, int nwords, int* flag)
{
    int i = blockIdx.x * blockDim.x + threadIdx.x;
    int odd = 2 * i + 1;
    if (odd < nwords && w[odd] != 0) atomicOr(flag, 1);
}

__global__ void convert_kernel(const int* __restrict__ w, const int* __restrict__ flag,
                               int* __restrict__ src, int* __restrict__ dst, int E)
{
    int i = blockIdx.x * blockDim.x + threadIdx.x;
    if (i >= E) return;
    if (*flag == 0) { src[i] = w[2 * i]; dst[i] = w[2 * E + 2 * i]; }
    else            { src[i] = w[i];     dst[i] = w[E + i]; }
}

// ======================== CSR build ========================
__global__ void hist_kernel(const int* __restrict__ dst, int* __restrict__ deg, int E)
{
    int i = blockIdx.x * blockDim.x + threadIdx.x;
    if (i < E) atomicAdd(deg + dst[i], 1);
}

#define SCAN_T 1024
__global__ __launch_bounds__(SCAN_T) void scan_kernel(
    const int* __restrict__ deg, int* __restrict__ off, int n)
{
    __shared__ int part[SCAN_T];
    int t = threadIdx.x;
    int per = (n + SCAN_T - 1) / SCAN_T;
    int b0 = t * per, b1 = min(b0 + per, n);
    int s = 0;
    for (int i = b0; i < b1; ++i) s += deg[i];
    part[t] = s;
    __syncthreads();
    for (int d = 1; d < SCAN_T; d <<= 1) {
        int v = (t >= d) ? part[t - d] : 0;
        __syncthreads();
        part[t] += v;
        __syncthreads();
    }
    int run = (t == 0) ? 0 : part[t - 1];
    for (int i = b0; i < b1; ++i) { off[i] = run; run += deg[i]; }
    if (t == SCAN_T - 1) off[n] = run;
}

// emits src ids in dst-sorted order
__global__ void scatter_kernel(const int* __restrict__ src, const int* __restrict__ dst,
                               const int* __restrict__ off, int* __restrict__ cnt,
                               int* __restrict__ srcs, int E)
{
    int i = blockIdx.x * blockDim.x + threadIdx.x;
    if (i >= E) return;
    int d = dst[i];
    int pos = off[d] + atomicAdd(cnt + d, 1);
    srcs[pos] = src[i];
}

// ======================== attention logits ========================
__global__ void al_bf16_kernel(const ushort_t* __restrict__ h,
                               const float* __restrict__ a_s, const float* __restrict__ a_d,
                               float* __restrict__ als, float* __restrict__ ald,
                               int Nn, int Hh, int Cc)
{
    int wid  = (blockIdx.x * blockDim.x + threadIdx.x) >> 6;
    int lane = threadIdx.x & 63;
    if (wid >= Nn * Hh) return;
    int n = wid / Hh, hh = wid - n * Hh;
    const ushort_t* hp = h + (size_t)n * Hh * Cc + hh * Cc;
    float s1 = 0.f, s2 = 0.f;
    int c = lane * 2;
    if (c < Cc) {
        unsigned w = *reinterpret_cast<const unsigned*>(hp + c);
        float f0 = b2f((ushort_t)(w & 0xffffu)), f1 = b2f((ushort_t)(w >> 16));
        float2 as2 = *reinterpret_cast<const float2*>(a_s + hh * Cc + c);
        float2 ad2 = *reinterpret_cast<const float2*>(a_d + hh * Cc + c);
        s1 = f0 * as2.x + f1 * as2.y;
        s2 = f0 * ad2.x + f1 * ad2.y;
    }
#pragma unroll
    for (int o = 32; o; o >>= 1) {
        s1 += __shfl_down(s1, o);
        s2 += __shfl_down(s2, o);
    }
    if (lane == 0) { als[wid] = s1; ald[wid] = s2; }
}

// ======================== fused CSR segment softmax ========================
// One wave per dst node. Writes final alpha into ebuf in SORTED edge order.
template<int HH, int LOGH>
__global__ void softmax_csr_kernel(const float* __restrict__ als,
                                   const float* __restrict__ ald,
                                   const int* __restrict__ off,
                                   const int* __restrict__ srcs,
                                   float* __restrict__ ebuf, int Nn)
{
    const int d = blockIdx.x * (blockDim.x >> 6) + (threadIdx.x >> 6);
    if (d >= Nn) return;
    const int lane = threadIdx.x & 63;
    const int h = lane & (HH - 1);
    const int j = lane >> LOGH;
    const int JS = 64 >> LOGH;
    const int start = off[d], end = off[d + 1];
    const float aldv = ald[d * HH + h];
    float m = -1e30f, ssum = 0.f;
    for (int base = start; base < end; base += JS) {
        int e = base + j;
        float v = -1e30f;
        if (e < end) {
            int s = srcs[e];
            float x = als[s * HH + h] + aldv;
            v = (x > 0.f) ? x : NEG_SLOPE * x;
            ebuf[(size_t)e * HH + h] = v;
        }
        float cm = v;
#pragma unroll
        for (int o = HH; o <= 32; o <<= 1) cm = fmaxf(cm, __shfl_xor(cm, o));
        float mnew = fmaxf(m, cm);
        float ex = (e < end) ? __expf(v - mnew) : 0.f;
#pragma unroll
        for (int o = HH; o <= 32; o <<= 1) ex += __shfl_xor(ex, o);
        ssum = ssum * __expf(m - mnew) + ex;
        m = mnew;
    }
    float rs = 1.f / ssum;
    for (int base = start; base < end; base += JS) {
        int e = base + j;
        if (e < end) {
            float v = ebuf[(size_t)e * HH + h];
            ebuf[(size_t)e * HH + h] = __expf(v - m) * rs;
        }
    }
}

// ======================== CSR aggregation (fused bias+act+bf16 out) ========================
#define AGG_CHUNK 8
__global__ void agg_csr_kernel(const ushort_t* __restrict__ h,
                               const float* __restrict__ ebuf,
                               const int* __restrict__ off, const int* __restrict__ srcs,
                               const float* __restrict__ bias,
                               ushort_t* __restrict__ outb,
                               int Hh, int F, int ostride, int act)
{
    const int d = blockIdx.x;
    const int t = threadIdx.x;
    __shared__ float alphaL[AGG_CHUNK][NH];
    __shared__ int   srcL[AGG_CHUNK];
    const int start = off[d], end = off[d + 1];
    const int nact = F >> 3;
    const int head = (t * 8) / CH;
    float acc[8] = {0.f, 0.f, 0.f, 0.f, 0.f, 0.f, 0.f, 0.f};
    for (int base = start; base < end; base += AGG_CHUNK) {
        int nb = min(AGG_CHUNK, end - base);
        if (t < nb) srcL[t] = srcs[base + t];
        if (t < nb * Hh) {
            int j = t / Hh, hh = t - j * Hh;
            alphaL[j][hh] = ebuf[(size_t)(base + j) * Hh + hh];
        }
        __syncthreads();
        if (t < nact) {
            for (int j = 0; j < nb; ++j) {
                int s = srcL[j];
                float a = alphaL[j][head];
                short8 v = *reinterpret_cast<const short8*>(h + (size_t)s * F + t * 8);
#pragma unroll
                for (int k = 0; k < 8; ++k)
                    acc[k] = fmaf(b2f((ushort_t)v[k]), a, acc[k]);
            }
        }
        __syncthreads();
    }
    if (t < nact) {
        short8 o;
#pragma unroll
        for (int k = 0; k < 8; ++k) {
            float v = acc[k] + bias[t * 8 + k];
            if (act) v = (v > 0.f) ? v : expm1f(v);
            o[k] = (short)f2b(v);
        }
        *reinterpret_cast<short8*>(outb + (size_t)d * ostride + t * 8) = o;
    }
}

// ======================== launch ========================
extern "C" void kernel_launch(void* const* d_in, const int* in_sizes, int n_in,
                              void* d_out, int out_size, void* d_ws, size_t ws_size,
                              hipStream_t stream)
{
    const float* x   = (const float*)d_in[0];
    const int*   ei  = (const int*)  d_in[1];
    const float* W1  = (const float*)d_in[2];
    const float* a1s = (const float*)d_in[3];
    const float* a1d = (const float*)d_in[4];
    const float* b1  = (const float*)d_in[5];
    const float* W2  = (const float*)d_in[6];
    const float* a2s = (const float*)d_in[7];
    const float* a2d = (const float*)d_in[8];
    const float* b2  = (const float*)d_in[9];
    const float* W3  = (const float*)d_in[10];
    const float* a3s = (const float*)d_in[11];
    const float* a3d = (const float*)d_in[12];
    const float* b3  = (const float*)d_in[13];
    const float* fcW = (const float*)d_in[14];
    const float* fcb = (const float*)d_in[15];

    float* out = (float*)d_out;
    const int N = N_NODES, E = N_EDGES;
    const int F16 = NH * CH;                 // 1920

    // ---- scratch inside d_out (FC overwrites all of d_out last)
    ushort_t* hraw = (ushort_t*)out;                     // [MPAD][1920]
    ushort_t* hagg = hraw + (size_t)MPAD * F16;          // [MPAD][1920]
    ushort_t* xb   = hagg + (size_t)MPAD * F16;          // [MPAD][128]
    ushort_t* W1t  = xb   + (size_t)MPAD * F_IN;         // [1920][128]
    ushort_t* W2t  = W1t  + (size_t)F16 * F_IN;          // [1920][1920]
    ushort_t* W3t  = W2t  + (size_t)F16 * F16;           // [128][1920]
    ushort_t* h3raw= W3t  + (size_t)128 * F16;           // [N][120]
    float*    als  = (float*)(h3raw + (size_t)N * CH);
    float*    ald  = als + (size_t)N * NH;
    float*    ebuf = ald + (size_t)N * NH;               // [E][16] sorted alpha
    int*      srcv = (int*)(ebuf + (size_t)E * NH);
    int*      dstv = srcv + E;
    int*      srcs = dstv + E;
    int*      flag = srcs + E;
    int*      deg  = flag + 1;                           // [N]
    int*      offv = deg + N;                            // [N+1]
    int*      cnt  = offv + N + 1;                       // [N]
    // ---- d_ws: FC inputs (read while FC writes d_out)
    ushort_t* h3bb = (ushort_t*)d_ws;                    // [MPAD][128]
    ushort_t* fcWt = h3bb + (size_t)MPAD * 128;          // [MPAD][128]

    // ---- edge decode + CSR build
    hipMemsetAsync(flag, 0, sizeof(int), stream);
    detect_kernel <<<(E + 255) / 256, 256, 0, stream>>>(ei, 2 * E, flag);
    convert_kernel<<<(E + 255) / 256, 256, 0, stream>>>(ei, flag, srcv, dstv, E);
    hipMemsetAsync(deg, 0, (size_t)N * 4, stream);
    hipMemsetAsync(cnt, 0, (size_t)N * 4, stream);
    hist_kernel   <<<(E + 255) / 256, 256, 0, stream>>>(dstv, deg, E);
    scan_kernel   <<<1, SCAN_T, 0, stream>>>(deg, offv, N);
    scatter_kernel<<<(E + 255) / 256, 256, 0, stream>>>(srcv, dstv, offv, cnt, srcs, E);

    // ---- input/weight prep
    f2b_kernel<<<(N * F_IN / 4 + 255) / 256, 256, 0, stream>>>(x, xb, N * F_IN);
    dim3 tb(256);
    transpose_b_kernel<<<dim3(F_IN / 32, F16 / 32), tb, 0, stream>>>(W1, W1t, F_IN, F16, F_IN);
    transpose_b_kernel<<<dim3(F16 / 32, F16 / 32), tb, 0, stream>>>(W2, W2t, F16, F16, F16);
    transpose_b_kernel<<<dim3(F16 / 32, 128 / 32), tb, 0, stream>>>(W3, W3t, F16, CH, F16);
    transpose_b_kernel<<<dim3(128 / 32, MPAD / 32), tb, 0, stream>>>(fcW, fcWt, CH, N, 128);
    hipMemsetAsync(h3bb, 0, (size_t)MPAD * 128 * 2, stream);

    dim3 gBig(F16 / GBN, MPAD / GBM);        // (15,79)

    // =============== layer 1 ===============
    gemm_mfma_kernel<0, 1><<<gBig, 256, 0, stream>>>(xb, W1t, nullptr, hraw, N, F16, F_IN);
    al_bf16_kernel<<<(N * NH + 3) / 4, 256, 0, stream>>>(hraw, a1s, a1d, als, ald, N, NH, CH);
    softmax_csr_kernel<16, 4><<<(N + 3) / 4, 256, 0, stream>>>(als, ald, offv, srcs, ebuf, N);
    agg_csr_kernel<<<N, 256, 0, stream>>>(hraw, ebuf, offv, srcs, b1, hagg, NH, F16, F16, 1);

    // =============== layer 2 ===============
    gemm_mfma_kernel<0, 1><<<gBig, 256, 0, stream>>>(hagg, W2t, nullptr, hraw, N, F16, F16);
    al_bf16_kernel<<<(N * NH + 3) / 4, 256, 0, stream>>>(hraw, a2s, a2d, als, ald, N, NH, CH);
    softmax_csr_kernel<16, 4><<<(N + 3) / 4, 256, 0, stream>>>(als, ald, offv, srcs, ebuf, N);
    agg_csr_kernel<<<N, 256, 0, stream>>>(hraw, ebuf, offv, srcs, b2, hagg, NH, F16, F16, 1);

    // =============== layer 3 (H=1) ===============
    dim3 gL3(1, MPAD / GBM);
    gemm_mfma_kernel<0, 1><<<gL3, 256, 0, stream>>>(hagg, W3t, nullptr, h3raw, N, CH, F16);
    al_bf16_kernel<<<(N + 3) / 4, 256, 0, stream>>>(h3raw, a3s, a3d, als, ald, N, 1, CH);
    softmax_csr_kernel<1, 0><<<(N + 3) / 4, 256, 0, stream>>>(als, ald, offv, srcs, ebuf, N);
    agg_csr_kernel<<<N, 64, 0, stream>>>(h3raw, ebuf, offv, srcs, b3, h3bb, 1, CH, 128, 0);

    // =============== FC + ReLU ===============
    dim3 gFC(MPAD / GBN, MPAD / GBM);        // (79,79); guards trim to 10000
    gemm_mfma_kernel<1, 0><<<gFC, 256, 0, stream>>>(h3bb, fcWt, fcb, out, N, N, 128);
}